// Round 11
// baseline (996.478 us; speedup 1.0000x reference)
//
#include <hip/hip_runtime.h>
#include <cstddef>

// ---------------- weight prep: conv1 w (32,3,11,11) -> wT1 [r=ic*11+kh][oc][12]
__global__ __launch_bounds__(256) void prep_w1(const float* __restrict__ w,
                                               float* __restrict__ wT) {
  const int j = blockIdx.x * 256 + threadIdx.x;
  if (j >= 33 * 32 * 12) return;
  const int kw = j % 12, oc = (j / 12) % 32, r = j / (12 * 32);
  wT[j] = (kw < 11) ? w[oc * 363 + r * 11 + kw] : 0.f;
}

// ---------------- weight prep: conv2 w (16,32,9,9) -> wT2b [ic][oc][84]
__global__ __launch_bounds__(256) void prep_w2b(const float* __restrict__ w,
                                                float* __restrict__ wT) {
  const int j = blockIdx.x * 256 + threadIdx.x;
  if (j >= 32 * 16 * 84) return;
  const int kp = j % 84, oc = (j / 84) % 16, ic = j / (84 * 16);
  wT[j] = (kp < 81) ? w[(size_t)oc * 2592 + ic * 81 + kp] : 0.f;
}

// ---------------- conv1 v4: weights direct from global wT1 (broadcast, L2-hot)
__global__ __launch_bounds__(256, 4) void conv1_v4(const float* __restrict__ x,
                                                   const float* __restrict__ wT,
                                                   const float* __restrict__ bias,
                                                   float* __restrict__ out) {
  __shared__ __align__(16) float xs[3][26][44];
  const int wt = blockIdx.x, ht = blockIdx.y, b = blockIdx.z;
  const int tid = threadIdx.x;
  const int posg = tid & 31;
  const int ocg = tid >> 5;
  const int owg = posg & 1;
  const int ohl = posg >> 1;
  const int ih0 = ht * 16, iw0 = wt * 32;

  for (int j = tid; j < 3 * 26 * 42; j += 256) {
    const int ic = j / 1092, r = (j % 1092) / 42, c = j % 42;
    const int ih = min(ih0 + r, 151), iw = min(iw0 + c, 151);
    xs[ic][r][c] = x[((size_t)b * 3 + ic) * 23104 + ih * 152 + iw];
  }
  __syncthreads();

  const int oh = ih0 + ohl;
  if (oh >= 142) return;
  float acc[4][16] = {};
  for (int ic = 0; ic < 3; ++ic) {
    for (int kh = 0; kh < 11; ++kh) {
      const int r = ic * 11 + kh;
      float xv[28];
      const float* xr = &xs[ic][ohl + kh][owg * 16];
      #pragma unroll
      for (int j = 0; j < 7; ++j) *(float4*)&xv[4 * j] = *(const float4*)&xr[4 * j];
      float wv[4][12];
      #pragma unroll
      for (int o = 0; o < 4; ++o) {
        const float* wr = &wT[(r * 32 + ocg * 4 + o) * 12];
        *(float4*)&wv[o][0] = *(const float4*)&wr[0];
        *(float4*)&wv[o][4] = *(const float4*)&wr[4];
        *(float4*)&wv[o][8] = *(const float4*)&wr[8];
      }
      #pragma unroll
      for (int kw = 0; kw < 11; ++kw)
        #pragma unroll
        for (int o = 0; o < 4; ++o)
          #pragma unroll
          for (int p = 0; p < 16; ++p)
            acc[o][p] += xv[kw + p] * wv[o][kw];
    }
  }

  const int ow0 = iw0 + owg * 16;
  #pragma unroll
  for (int o = 0; o < 4; ++o) {
    const int oc = ocg * 4 + o;
    const float bv = bias[oc];
    float* op = &out[(((size_t)b * 32 + oc) * 142 + oh) * 142 + ow0];
    if (ow0 + 16 <= 142) {
      #pragma unroll
      for (int p = 0; p < 16; p += 2) {
        float2 rv;
        rv.x = fmaxf(acc[o][p] + bv, 0.f);
        rv.y = fmaxf(acc[o][p + 1] + bv, 0.f);
        *(float2*)&op[p] = rv;
      }
    } else {
      for (int p = 0; p < 16; ++p)
        if (ow0 + p < 142) op[p] = fmaxf(acc[o][p] + bv, 0.f);
    }
  }
}

// ---------------- maxpool 3x3 s2 p1
__global__ __launch_bounds__(256) void pool_3_2_1(const float* __restrict__ in,
                                                  float* __restrict__ out) {
  const int idx = blockIdx.x * 256 + threadIdx.x;
  const int total = 32 * 32 * 71 * 71;
  if (idx >= total) return;
  const int ow = idx % 71;
  const int oh = (idx / 71) % 71;
  const int bc = idx / (71 * 71);
  const float* base = in + (size_t)bc * 142 * 142;
  float m = -1e30f;
  #pragma unroll
  for (int kh = 0; kh < 3; ++kh) {
    const int ih = oh * 2 - 1 + kh;
    if (ih < 0 || ih >= 142) continue;
    #pragma unroll
    for (int kw = 0; kw < 3; ++kw) {
      const int iw = ow * 2 - 1 + kw;
      if (iw < 0 || iw >= 142) continue;
      m = fmaxf(m, base[ih * 142 + iw]);
    }
  }
  out[idx] = m;
}

// ---------------- transpose p1 (b,c,71,71) -> p1T [c][pos 5041][b32]
__global__ __launch_bounds__(256) void t_p1(const float* __restrict__ in,
                                            float* __restrict__ outT) {
  __shared__ float tile[64][33];
  const int c = blockIdx.x;
  const int pos0 = blockIdx.y * 64;
  const int tid = threadIdx.x;
  for (int j = tid; j < 2048; j += 256) {
    const int pl = j & 63;
    const int b = j >> 6;
    const int pos = min(pos0 + pl, 5040);
    tile[pl][b] = in[((size_t)b * 32 + c) * 5041 + pos];
  }
  __syncthreads();
  for (int j = tid; j < 2048; j += 256) {
    const int b = j & 31;
    const int pl = j >> 5;
    const int pos = pos0 + pl;
    if (pos < 5041) outT[((size_t)c * 5041 + pos) * 32 + b] = tile[pl][b];
  }
}

// ---------------- conv2 v5: lc_v8-style, NO LDS/barriers; ic-split x8 (4 ic each)
// for ~8k waves (97% capacity) to hide L3 latency on p1T reads.
__global__ __launch_bounds__(256, 4) void conv2_v5(const float* __restrict__ xt,
                                                   const float* __restrict__ wT,
                                                   float* __restrict__ part) {
  const int tid = threadIdx.x;
  const int lane = tid & 63, wvi = tid >> 6;
  const int p = lane >> 4;
  const int og = (lane >> 3) & 1;
  const int bg = lane & 7;
  int mypos = blockIdx.x * 16 + wvi * 4 + p;
  if (mypos >= 3969) mypos = 3968;
  const int icg = blockIdx.y;                // 0..7, 4 ic each
  const int oh = mypos / 63, ow = mypos % 63;

  float acc[8][4] = {};
  #pragma unroll 1
  for (int ics = 0; ics < 4; ++ics) {
    const int ic = icg * 4 + ics;
    const float* wic = wT + ((size_t)ic * 16 + og * 8) * 84;
    const float* xic = xt + ((size_t)ic * 5041 + oh * 71 + ow) * 32 + bg * 4;
    #pragma unroll 1
    for (int kc = 0; kc < 20; ++kc) {
      float4 wf[8];
      #pragma unroll
      for (int o = 0; o < 8; ++o)
        wf[o] = *(const float4*)&wic[o * 84 + kc * 4];
      float4 xv[4];
      #pragma unroll
      for (int kk = 0; kk < 4; ++kk) {
        const int k = kc * 4 + kk;
        const int kh = k / 9, kw = k - kh * 9;
        xv[kk] = *(const float4*)&xic[(kh * 71 + kw) * 32];
      }
      #pragma unroll
      for (int kk = 0; kk < 4; ++kk) {
        const float4 xk = xv[kk];
        #pragma unroll
        for (int o = 0; o < 8; ++o) {
          const float wv = (kk == 0) ? wf[o].x
                         : (kk == 1) ? wf[o].y
                         : (kk == 2) ? wf[o].z
                                     : wf[o].w;
          acc[o][0] += wv * xk.x;
          acc[o][1] += wv * xk.y;
          acc[o][2] += wv * xk.z;
          acc[o][3] += wv * xk.w;
        }
      }
    }
    {  // tail k = 80 (kh=8, kw=8)
      const float4 xk = *(const float4*)&xic[(8 * 71 + 8) * 32];
      #pragma unroll
      for (int o = 0; o < 8; ++o) {
        const float wv = wic[o * 84 + 80];
        acc[o][0] += wv * xk.x;
        acc[o][1] += wv * xk.y;
        acc[o][2] += wv * xk.z;
        acc[o][3] += wv * xk.w;
      }
    }
  }

  float* pp = part + (size_t)icg * 2032128;
  #pragma unroll
  for (int o = 0; o < 8; ++o) {
    const int oc = og * 8 + o;
    #pragma unroll
    for (int i = 0; i < 4; ++i) {
      const int b = bg * 4 + i;
      pp[(((size_t)b * 16 + oc) * 63 + oh) * 63 + ow] = acc[o][i];
    }
  }
}

// ---------------- combineT: sum nicg partials + bias + relu, output TRANSPOSED
__global__ __launch_bounds__(256) void combineT(const float* __restrict__ part,
                                                const float* __restrict__ bias,
                                                float* __restrict__ outT,
                                                int npos, int total, int nicg,
                                                int bias_pp) {
  __shared__ float tile[64][33];
  const int oc = blockIdx.x;
  const int pos0 = blockIdx.y * 64;
  const int tid = threadIdx.x;
  for (int j = tid; j < 2048; j += 256) {
    const int pl = j & 63;
    const int b = j >> 6;
    const int pos = min(pos0 + pl, npos - 1);
    const size_t idx = ((size_t)b * 16 + oc) * npos + pos;
    float v = 0.f;
    for (int g = 0; g < nicg; ++g) v += part[idx + (size_t)g * total];
    v += bias_pp ? bias[oc * npos + pos] : bias[oc];
    tile[pl][b] = fmaxf(v, 0.f);
  }
  __syncthreads();
  for (int j = tid; j < 2048; j += 256) {
    const int b = j & 31;
    const int pl = j >> 5;
    const int pos = pos0 + pl;
    if (pos < npos) outT[((size_t)oc * npos + pos) * 32 + b] = tile[pl][b];
  }
}

// ---------------- local conv v8: NO LDS. x pre-transposed to [ic][pos][b32].
template <int KH, int S, int IH, int OH>
__global__ __launch_bounds__(256, 4) void lc_v8(const float* __restrict__ xt,
                                                const float* __restrict__ w,
                                                float* __restrict__ part) {
  constexpr int KHW = KH * KH;
  constexpr int NPOS = OH * OH;
  constexpr int WOC = 16 * KHW;
  constexpr int KC4 = KHW / 4;               // 20 / 12 / 6
  const int tid = threadIdx.x;
  const int lane = tid & 63, wvi = tid >> 6;
  const int p = lane >> 4;
  const int og = (lane >> 3) & 1;
  const int bg = lane & 7;
  int mypos = blockIdx.x * 16 + wvi * 4 + p;
  if (mypos >= NPOS) mypos = NPOS - 1;
  const int icg = blockIdx.y;
  const int oh = mypos / OH, ow = mypos % OH;

  float acc[8][4] = {};
  #pragma unroll 1
  for (int ics = 0; ics < 2; ++ics) {
    const int ic = icg * 2 + ics;
    const float* wic = w + ((size_t)mypos * 16 + og * 8) * WOC + (size_t)ic * KHW;
    const float* xic =
        xt + (((size_t)ic * IH + oh * S) * IH + ow * S) * 32 + bg * 4;
    #pragma unroll 1
    for (int kc = 0; kc < KC4; ++kc) {
      float4 wf[8];
      #pragma unroll
      for (int o = 0; o < 8; ++o)
        wf[o] = *(const float4*)&wic[o * WOC + kc * 4];
      float4 xv[4];
      #pragma unroll
      for (int kk = 0; kk < 4; ++kk) {
        const int k = kc * 4 + kk;
        const int kh = k / KH, kw = k - kh * KH;
        xv[kk] = *(const float4*)&xic[(kh * IH + kw) * 32];
      }
      #pragma unroll
      for (int kk = 0; kk < 4; ++kk) {
        const float4 xk = xv[kk];
        #pragma unroll
        for (int o = 0; o < 8; ++o) {
          const float wv = (kk == 0) ? wf[o].x
                         : (kk == 1) ? wf[o].y
                         : (kk == 2) ? wf[o].z
                                     : wf[o].w;
          acc[o][0] += wv * xk.x;
          acc[o][1] += wv * xk.y;
          acc[o][2] += wv * xk.z;
          acc[o][3] += wv * xk.w;
        }
      }
    }
    {  // tail k = KHW-1
      const int k = KHW - 1;
      const float4 xk = *(const float4*)&xic[((KH - 1) * IH + (KH - 1)) * 32];
      #pragma unroll
      for (int o = 0; o < 8; ++o) {
        const float wv = wic[o * WOC + k];
        acc[o][0] += wv * xk.x;
        acc[o][1] += wv * xk.y;
        acc[o][2] += wv * xk.z;
        acc[o][3] += wv * xk.w;
      }
    }
  }

  float* pp = part + (size_t)icg * (32 * 16 * NPOS);
  #pragma unroll
  for (int o = 0; o < 8; ++o) {
    const int oc = og * 8 + o;
    #pragma unroll
    for (int i = 0; i < 4; ++i) {
      const int b = bg * 4 + i;
      pp[(((size_t)b * 16 + oc) * OH + oh) * OH + ow] = acc[o][i];
    }
  }
}

// ---------------- fc1: reg-tiled GEMM; xt = h5T ([oc][pos][b] == [k][b])
__global__ __launch_bounds__(256) void fc1_v2(const float* __restrict__ xt,
                                              const float* __restrict__ w,
                                              const float* __restrict__ bias,
                                              float* __restrict__ out) {
  const int lane = threadIdx.x & 63;
  const int b0 = (threadIdx.x >> 6) * 8;
  const int n0 = blockIdx.x * 8;
  float acc[8][8] = {};
  for (int it = 0; it < 28; ++it) {
    const int kb = it * 256 + lane * 4;
    float4 wf[8], xa[4], xb[4];
    if (kb < 7056) {
      #pragma unroll
      for (int n = 0; n < 8; ++n)
        wf[n] = *(const float4*)&w[(size_t)(n0 + n) * 7056 + kb];
      #pragma unroll
      for (int j = 0; j < 4; ++j) {
        xa[j] = *(const float4*)&xt[(size_t)(kb + j) * 32 + b0];
        xb[j] = *(const float4*)&xt[(size_t)(kb + j) * 32 + b0 + 4];
      }
    } else {
      #pragma unroll
      for (int n = 0; n < 8; ++n) wf[n] = make_float4(0.f, 0.f, 0.f, 0.f);
      #pragma unroll
      for (int j = 0; j < 4; ++j) {
        xa[j] = make_float4(0.f, 0.f, 0.f, 0.f);
        xb[j] = make_float4(0.f, 0.f, 0.f, 0.f);
      }
    }
    #pragma unroll
    for (int n = 0; n < 8; ++n) {
      const float wk[4] = {wf[n].x, wf[n].y, wf[n].z, wf[n].w};
      #pragma unroll
      for (int j = 0; j < 4; ++j) {
        acc[n][0] += wk[j] * xa[j].x;
        acc[n][1] += wk[j] * xa[j].y;
        acc[n][2] += wk[j] * xa[j].z;
        acc[n][3] += wk[j] * xa[j].w;
        acc[n][4] += wk[j] * xb[j].x;
        acc[n][5] += wk[j] * xb[j].y;
        acc[n][6] += wk[j] * xb[j].z;
        acc[n][7] += wk[j] * xb[j].w;
      }
    }
  }
  #pragma unroll
  for (int n = 0; n < 8; ++n)
    #pragma unroll
    for (int c = 0; c < 8; ++c)
      #pragma unroll
      for (int m = 1; m < 64; m <<= 1)
        acc[n][c] += __shfl_xor(acc[n][c], m, 64);
  float val = 0.f;
  #pragma unroll
  for (int n = 0; n < 8; ++n)
    #pragma unroll
    for (int c = 0; c < 8; ++c)
      if (lane == n * 8 + c) val = acc[n][c];
  const int n_l = lane >> 3, b_l = lane & 7;
  out[(size_t)(b0 + b_l) * 4096 + n0 + n_l] = val + bias[n0 + n_l];
}

extern "C" void kernel_launch(void* const* d_in, const int* in_sizes, int n_in,
                              void* d_out, int out_size, void* d_ws, size_t ws_size,
                              hipStream_t stream) {
  const float* x       = (const float*)d_in[0];
  const float* conv1_w = (const float*)d_in[1];
  const float* conv1_b = (const float*)d_in[2];
  const float* conv2_w = (const float*)d_in[3];
  const float* conv2_b = (const float*)d_in[4];
  const float* lc1_w   = (const float*)d_in[5];
  const float* lc1_b   = (const float*)d_in[6];
  const float* lc2_w   = (const float*)d_in[7];
  const float* lc2_b   = (const float*)d_in[8];
  const float* lc3_w   = (const float*)d_in[9];
  const float* lc3_b   = (const float*)d_in[10];
  const float* fc1_w   = (const float*)d_in[11];
  const float* fc1_b   = (const float*)d_in[12];
  float* out = (float*)d_out;
  char* ws = (char*)d_ws;

  // timeline-aware layout (bytes), budget ~111.4 MB:
  float* h1   = (float*)(ws + 0);          // 82,591,744 (live: conv1->pool)
  float* p1   = (float*)(ws + 82591744);   // 20,647,936 (live: pool->t_p1)
  float* wT1  = (float*)(ws + 82591744);   // 50,688 (conv1 only; dead before pool writes p1)
  float* p1T  = (float*)(ws + 0);          // 20,647,936 (after pool; h1 dead)
  float* wT2  = (float*)(ws + 20971520);   // 172,032
  float* c2p  = (float*)(ws + 21233664);   // 8*8,128,512 = 65,028,096 (ends 86.3MB; dead after combineT)
  float* h2T  = (float*)(ws + 103239680);  //  8,128,512
  float* h3T  = (float*)(ws + 0);          //  6,195,200 (p1T dead by then)
  float* h4T  = (float*)(ws + 8388608);    //  1,280,000
  float* h5T  = (float*)(ws + 16777216);   //    903,168
  float* lcp  = (float*)(ws + 41943040);   // 49,561,600 (lc partials)

  prep_w1<<<50, 256, 0, stream>>>(conv1_w, wT1);
  conv1_v4<<<dim3(5, 9, 32), 256, 0, stream>>>(x, wT1, conv1_b, h1);
  pool_3_2_1<<<20164, 256, 0, stream>>>(h1, p1);
  t_p1<<<dim3(32, 79), 256, 0, stream>>>(p1, p1T);
  prep_w2b<<<168, 256, 0, stream>>>(conv2_w, wT2);
  conv2_v5<<<dim3(249, 8), 256, 0, stream>>>(p1T, wT2, c2p);
  combineT<<<dim3(16, 63), 256, 0, stream>>>(c2p, conv2_b, h2T, 3969, 2032128, 8, 0);

  lc_v8<9, 1, 63, 55><<<dim3(190, 8), 256, 0, stream>>>(h2T, lc1_w, lcp);
  combineT<<<dim3(16, 48), 256, 0, stream>>>(lcp, lc1_b, h3T, 3025, 1548800, 8, 1);
  lc_v8<7, 2, 55, 25><<<dim3(40, 8), 256, 0, stream>>>(h3T, lc2_w, lcp);
  combineT<<<dim3(16, 10), 256, 0, stream>>>(lcp, lc2_b, h4T, 625, 320000, 8, 1);
  lc_v8<5, 1, 25, 21><<<dim3(28, 8), 256, 0, stream>>>(h4T, lc3_w, lcp);
  combineT<<<dim3(16, 7), 256, 0, stream>>>(lcp, lc3_b, h5T, 441, 225792, 8, 1);

  fc1_v2<<<512, 256, 0, stream>>>(h5T, fc1_w, fc1_b, out);
}

// Round 12
// 776.007 us; speedup vs baseline: 1.2841x; 1.2841x over previous
//
#include <hip/hip_runtime.h>
#include <cstddef>

typedef __attribute__((ext_vector_type(8))) short bf16x8;
typedef __attribute__((ext_vector_type(4))) float f32x4;

__device__ inline unsigned short f2bf(float f) {
  unsigned int u = __float_as_uint(f);
  unsigned int r = (u + 0x7FFFu + ((u >> 16) & 1u)) >> 16;
  return (unsigned short)r;
}

// ---------------- weight prep: conv1 w (32,3,11,11) -> wT1 [r=ic*11+kh][oc][12]
__global__ __launch_bounds__(256) void prep_w1(const float* __restrict__ w,
                                               float* __restrict__ wT) {
  const int j = blockIdx.x * 256 + threadIdx.x;
  if (j >= 33 * 32 * 12) return;
  const int kw = j % 12, oc = (j / 12) % 32, r = j / (12 * 32);
  wT[j] = (kw < 11) ? w[oc * 363 + r * 11 + kw] : 0.f;
}

// ---------------- conv1 v4: weights direct from global wT1 (broadcast, L2-hot)
__global__ __launch_bounds__(256, 4) void conv1_v4(const float* __restrict__ x,
                                                   const float* __restrict__ wT,
                                                   const float* __restrict__ bias,
                                                   float* __restrict__ out) {
  __shared__ __align__(16) float xs[3][26][44];
  const int wt = blockIdx.x, ht = blockIdx.y, b = blockIdx.z;
  const int tid = threadIdx.x;
  const int posg = tid & 31;
  const int ocg = tid >> 5;
  const int owg = posg & 1;
  const int ohl = posg >> 1;
  const int ih0 = ht * 16, iw0 = wt * 32;

  for (int j = tid; j < 3 * 26 * 42; j += 256) {
    const int ic = j / 1092, r = (j % 1092) / 42, c = j % 42;
    const int ih = min(ih0 + r, 151), iw = min(iw0 + c, 151);
    xs[ic][r][c] = x[((size_t)b * 3 + ic) * 23104 + ih * 152 + iw];
  }
  __syncthreads();

  const int oh = ih0 + ohl;
  if (oh >= 142) return;
  float acc[4][16] = {};
  for (int ic = 0; ic < 3; ++ic) {
    for (int kh = 0; kh < 11; ++kh) {
      const int r = ic * 11 + kh;
      float xv[28];
      const float* xr = &xs[ic][ohl + kh][owg * 16];
      #pragma unroll
      for (int j = 0; j < 7; ++j) *(float4*)&xv[4 * j] = *(const float4*)&xr[4 * j];
      float wv[4][12];
      #pragma unroll
      for (int o = 0; o < 4; ++o) {
        const float* wr = &wT[(r * 32 + ocg * 4 + o) * 12];
        *(float4*)&wv[o][0] = *(const float4*)&wr[0];
        *(float4*)&wv[o][4] = *(const float4*)&wr[4];
        *(float4*)&wv[o][8] = *(const float4*)&wr[8];
      }
      #pragma unroll
      for (int kw = 0; kw < 11; ++kw)
        #pragma unroll
        for (int o = 0; o < 4; ++o)
          #pragma unroll
          for (int p = 0; p < 16; ++p)
            acc[o][p] += xv[kw + p] * wv[o][kw];
    }
  }

  const int ow0 = iw0 + owg * 16;
  #pragma unroll
  for (int o = 0; o < 4; ++o) {
    const int oc = ocg * 4 + o;
    const float bv = bias[oc];
    float* op = &out[(((size_t)b * 32 + oc) * 142 + oh) * 142 + ow0];
    if (ow0 + 16 <= 142) {
      #pragma unroll
      for (int p = 0; p < 16; p += 2) {
        float2 rv;
        rv.x = fmaxf(acc[o][p] + bv, 0.f);
        rv.y = fmaxf(acc[o][p + 1] + bv, 0.f);
        *(float2*)&op[p] = rv;
      }
    } else {
      for (int p = 0; p < 16; ++p)
        if (ow0 + p < 142) op[p] = fmaxf(acc[o][p] + bv, 0.f);
    }
  }
}

// ---------------- maxpool 3x3 s2 p1
__global__ __launch_bounds__(256) void pool_3_2_1(const float* __restrict__ in,
                                                  float* __restrict__ out) {
  const int idx = blockIdx.x * 256 + threadIdx.x;
  const int total = 32 * 32 * 71 * 71;
  if (idx >= total) return;
  const int ow = idx % 71;
  const int oh = (idx / 71) % 71;
  const int bc = idx / (71 * 71);
  const float* base = in + (size_t)bc * 142 * 142;
  float m = -1e30f;
  #pragma unroll
  for (int kh = 0; kh < 3; ++kh) {
    const int ih = oh * 2 - 1 + kh;
    if (ih < 0 || ih >= 142) continue;
    #pragma unroll
    for (int kw = 0; kw < 3; ++kw) {
      const int iw = ow * 2 - 1 + kw;
      if (iw < 0 || iw >= 142) continue;
      m = fmaxf(m, base[ih * 142 + iw]);
    }
  }
  out[idx] = m;
}

// ---------------- xb2: p1 (b,32,71,71) f32 -> [pos 5041][b32][ic32] bf16
__global__ __launch_bounds__(256) void t_xb2(const float* __restrict__ p1,
                                             unsigned short* __restrict__ xb) {
  __shared__ float tile[32][65];
  const int b = blockIdx.x;
  const int pos0 = blockIdx.y * 64;
  const int tid = threadIdx.x;
  for (int j = tid; j < 32 * 64; j += 256) {
    const int ic = j >> 6, pl = j & 63;
    const int pos = min(pos0 + pl, 5040);
    tile[ic][pl] = p1[((size_t)b * 32 + ic) * 5041 + pos];
  }
  __syncthreads();
  for (int j = tid; j < 64 * 32; j += 256) {
    const int pl = j >> 5, ic = j & 31;
    const int pos = pos0 + pl;
    if (pos < 5041) xb[((size_t)pos * 32 + b) * 32 + ic] = f2bf(tile[ic][pl]);
  }
}

// ---------------- wb2: conv2 w (16,32,9,9) -> [sp81][oc16][ic32] bf16
__global__ __launch_bounds__(256) void prep_wb2(const float* __restrict__ w,
                                                unsigned short* __restrict__ wb) {
  const int j = blockIdx.x * 256 + threadIdx.x;
  if (j >= 81 * 16 * 32) return;
  const int ic = j & 31, oc = (j >> 5) & 15, sp = j >> 9;
  wb[j] = f2bf(w[(size_t)oc * 2592 + ic * 81 + sp]);
}

// ---------------- conv2 via MFMA: wave = 1 pos; C[16oc][32b] = W[16][2592]X[2592][32b]
// K-step = 32 ic at one tap; 81 taps x 2 b-halves = 162 mfma_f32_16x16x32_bf16.
// Bias+relu fused; writes h2T [oc][pos][b32] directly.
__global__ __launch_bounds__(256) void conv2_mfma(const unsigned short* __restrict__ xb,
                                                  const unsigned short* __restrict__ wb,
                                                  const float* __restrict__ bias,
                                                  float* __restrict__ outT) {
  const int lane = threadIdx.x & 63;
  const int wvi = threadIdx.x >> 6;
  int pos = blockIdx.x * 4 + wvi;
  if (pos > 3968) pos = 3968;
  const int oh = pos / 63, ow = pos % 63;
  const int row = lane & 15;                    // A row (oc) / B col (b)
  const int kc = lane >> 4;                     // k-chunk 0..3
  f32x4 acc0 = {0.f, 0.f, 0.f, 0.f}, acc1 = {0.f, 0.f, 0.f, 0.f};
  const unsigned short* xbase = xb + (size_t)(oh * 71 + ow) * 1024;
  const int aoff = row * 32 + kc * 8;
  const int boff0 = aoff;                       // b = row
  const int boff1 = (row + 16) * 32 + kc * 8;   // b = row+16

  #pragma unroll
  for (int kh = 0; kh < 9; ++kh) {
    #pragma unroll
    for (int kw = 0; kw < 9; ++kw) {
      const int sp = kh * 9 + kw;
      const bf16x8 a = *(const bf16x8*)(wb + sp * 512 + aoff);
      const unsigned short* xp = xbase + (kh * 71 + kw) * 1024;
      const bf16x8 b0 = *(const bf16x8*)(xp + boff0);
      const bf16x8 b1 = *(const bf16x8*)(xp + boff1);
      acc0 = __builtin_amdgcn_mfma_f32_16x16x32_bf16(a, b0, acc0, 0, 0, 0);
      acc1 = __builtin_amdgcn_mfma_f32_16x16x32_bf16(a, b1, acc1, 0, 0, 0);
    }
  }

  // C/D: col(b)=lane&15, row(oc)=(lane>>4)*4+r
  #pragma unroll
  for (int r = 0; r < 4; ++r) {
    const int oc = kc * 4 + r;
    const float bv = bias[oc];
    outT[((size_t)oc * 3969 + pos) * 32 + row] = fmaxf(acc0[r] + bv, 0.f);
    outT[((size_t)oc * 3969 + pos) * 32 + 16 + row] = fmaxf(acc1[r] + bv, 0.f);
  }
}

// ---------------- combineT: sum nicg partials + bias + relu, output TRANSPOSED
__global__ __launch_bounds__(256) void combineT(const float* __restrict__ part,
                                                const float* __restrict__ bias,
                                                float* __restrict__ outT,
                                                int npos, int total, int nicg,
                                                int bias_pp) {
  __shared__ float tile[64][33];
  const int oc = blockIdx.x;
  const int pos0 = blockIdx.y * 64;
  const int tid = threadIdx.x;
  for (int j = tid; j < 2048; j += 256) {
    const int pl = j & 63;
    const int b = j >> 6;
    const int pos = min(pos0 + pl, npos - 1);
    const size_t idx = ((size_t)b * 16 + oc) * npos + pos;
    float v = 0.f;
    for (int g = 0; g < nicg; ++g) v += part[idx + (size_t)g * total];
    v += bias_pp ? bias[oc * npos + pos] : bias[oc];
    tile[pl][b] = fmaxf(v, 0.f);
  }
  __syncthreads();
  for (int j = tid; j < 2048; j += 256) {
    const int b = j & 31;
    const int pl = j >> 5;
    const int pos = pos0 + pl;
    if (pos < npos) outT[((size_t)oc * npos + pos) * 32 + b] = tile[pl][b];
  }
}

// ---------------- local conv v8: NO LDS. x pre-transposed to [ic][pos][b32].
template <int KH, int S, int IH, int OH>
__global__ __launch_bounds__(256, 4) void lc_v8(const float* __restrict__ xt,
                                                const float* __restrict__ w,
                                                float* __restrict__ part) {
  constexpr int KHW = KH * KH;
  constexpr int NPOS = OH * OH;
  constexpr int WOC = 16 * KHW;
  constexpr int KC4 = KHW / 4;               // 20 / 12 / 6
  const int tid = threadIdx.x;
  const int lane = tid & 63, wvi = tid >> 6;
  const int p = lane >> 4;
  const int og = (lane >> 3) & 1;
  const int bg = lane & 7;
  int mypos = blockIdx.x * 16 + wvi * 4 + p;
  if (mypos >= NPOS) mypos = NPOS - 1;
  const int icg = blockIdx.y;
  const int oh = mypos / OH, ow = mypos % OH;

  float acc[8][4] = {};
  #pragma unroll 1
  for (int ics = 0; ics < 2; ++ics) {
    const int ic = icg * 2 + ics;
    const float* wic = w + ((size_t)mypos * 16 + og * 8) * WOC + (size_t)ic * KHW;
    const float* xic =
        xt + (((size_t)ic * IH + oh * S) * IH + ow * S) * 32 + bg * 4;
    #pragma unroll 1
    for (int kc = 0; kc < KC4; ++kc) {
      float4 wf[8];
      #pragma unroll
      for (int o = 0; o < 8; ++o)
        wf[o] = *(const float4*)&wic[o * WOC + kc * 4];
      float4 xv[4];
      #pragma unroll
      for (int kk = 0; kk < 4; ++kk) {
        const int k = kc * 4 + kk;
        const int kh = k / KH, kw = k - kh * KH;
        xv[kk] = *(const float4*)&xic[(kh * IH + kw) * 32];
      }
      #pragma unroll
      for (int kk = 0; kk < 4; ++kk) {
        const float4 xk = xv[kk];
        #pragma unroll
        for (int o = 0; o < 8; ++o) {
          const float wv = (kk == 0) ? wf[o].x
                         : (kk == 1) ? wf[o].y
                         : (kk == 2) ? wf[o].z
                                     : wf[o].w;
          acc[o][0] += wv * xk.x;
          acc[o][1] += wv * xk.y;
          acc[o][2] += wv * xk.z;
          acc[o][3] += wv * xk.w;
        }
      }
    }
    {  // tail k = KHW-1
      const int k = KHW - 1;
      const float4 xk = *(const float4*)&xic[((KH - 1) * IH + (KH - 1)) * 32];
      #pragma unroll
      for (int o = 0; o < 8; ++o) {
        const float wv = wic[o * WOC + k];
        acc[o][0] += wv * xk.x;
        acc[o][1] += wv * xk.y;
        acc[o][2] += wv * xk.z;
        acc[o][3] += wv * xk.w;
      }
    }
  }

  float* pp = part + (size_t)icg * (32 * 16 * NPOS);
  #pragma unroll
  for (int o = 0; o < 8; ++o) {
    const int oc = og * 8 + o;
    #pragma unroll
    for (int i = 0; i < 4; ++i) {
      const int b = bg * 4 + i;
      pp[(((size_t)b * 16 + oc) * OH + oh) * OH + ow] = acc[o][i];
    }
  }
}

// ---------------- fc1: reg-tiled GEMM; xt = h5T ([oc][pos][b] == [k][b])
__global__ __launch_bounds__(256) void fc1_v2(const float* __restrict__ xt,
                                              const float* __restrict__ w,
                                              const float* __restrict__ bias,
                                              float* __restrict__ out) {
  const int lane = threadIdx.x & 63;
  const int b0 = (threadIdx.x >> 6) * 8;
  const int n0 = blockIdx.x * 8;
  float acc[8][8] = {};
  for (int it = 0; it < 28; ++it) {
    const int kb = it * 256 + lane * 4;
    float4 wf[8], xa[4], xb[4];
    if (kb < 7056) {
      #pragma unroll
      for (int n = 0; n < 8; ++n)
        wf[n] = *(const float4*)&w[(size_t)(n0 + n) * 7056 + kb];
      #pragma unroll
      for (int j = 0; j < 4; ++j) {
        xa[j] = *(const float4*)&xt[(size_t)(kb + j) * 32 + b0];
        xb[j] = *(const float4*)&xt[(size_t)(kb + j) * 32 + b0 + 4];
      }
    } else {
      #pragma unroll
      for (int n = 0; n < 8; ++n) wf[n] = make_float4(0.f, 0.f, 0.f, 0.f);
      #pragma unroll
      for (int j = 0; j < 4; ++j) {
        xa[j] = make_float4(0.f, 0.f, 0.f, 0.f);
        xb[j] = make_float4(0.f, 0.f, 0.f, 0.f);
      }
    }
    #pragma unroll
    for (int n = 0; n < 8; ++n) {
      const float wk[4] = {wf[n].x, wf[n].y, wf[n].z, wf[n].w};
      #pragma unroll
      for (int j = 0; j < 4; ++j) {
        acc[n][0] += wk[j] * xa[j].x;
        acc[n][1] += wk[j] * xa[j].y;
        acc[n][2] += wk[j] * xa[j].z;
        acc[n][3] += wk[j] * xa[j].w;
        acc[n][4] += wk[j] * xb[j].x;
        acc[n][5] += wk[j] * xb[j].y;
        acc[n][6] += wk[j] * xb[j].z;
        acc[n][7] += wk[j] * xb[j].w;
      }
    }
  }
  #pragma unroll
  for (int n = 0; n < 8; ++n)
    #pragma unroll
    for (int c = 0; c < 8; ++c)
      #pragma unroll
      for (int m = 1; m < 64; m <<= 1)
        acc[n][c] += __shfl_xor(acc[n][c], m, 64);
  float val = 0.f;
  #pragma unroll
  for (int n = 0; n < 8; ++n)
    #pragma unroll
    for (int c = 0; c < 8; ++c)
      if (lane == n * 8 + c) val = acc[n][c];
  const int n_l = lane >> 3, b_l = lane & 7;
  out[(size_t)(b0 + b_l) * 4096 + n0 + n_l] = val + bias[n0 + n_l];
}

extern "C" void kernel_launch(void* const* d_in, const int* in_sizes, int n_in,
                              void* d_out, int out_size, void* d_ws, size_t ws_size,
                              hipStream_t stream) {
  const float* x       = (const float*)d_in[0];
  const float* conv1_w = (const float*)d_in[1];
  const float* conv1_b = (const float*)d_in[2];
  const float* conv2_w = (const float*)d_in[3];
  const float* conv2_b = (const float*)d_in[4];
  const float* lc1_w   = (const float*)d_in[5];
  const float* lc1_b   = (const float*)d_in[6];
  const float* lc2_w   = (const float*)d_in[7];
  const float* lc2_b   = (const float*)d_in[8];
  const float* lc3_w   = (const float*)d_in[9];
  const float* lc3_b   = (const float*)d_in[10];
  const float* fc1_w   = (const float*)d_in[11];
  const float* fc1_b   = (const float*)d_in[12];
  float* out = (float*)d_out;
  char* ws = (char*)d_ws;

  // timeline-aware layout (bytes):
  float* h1             = (float*)(ws + 0);          // 82,591,744 (conv1->pool)
  float* p1             = (float*)(ws + 82591744);   // 20,647,936 (pool->t_xb2)
  float* wT1            = (float*)(ws + 82591744);   // 50,688 (conv1 only; dead before pool)
  unsigned short* xb2   = (unsigned short*)(ws + 0); // 10,323,968 (after pool; h1 dead)
  unsigned short* wb2   = (unsigned short*)(ws + 20971520); // 82,944
  float* h2T            = (float*)(ws + 103239680);  //  8,128,512
  float* h3T            = (float*)(ws + 0);          //  6,195,200 (xb2 dead by then)
  float* h4T            = (float*)(ws + 8388608);    //  1,280,000
  float* h5T            = (float*)(ws + 16777216);   //    903,168
  float* lcp            = (float*)(ws + 41943040);   // 49,561,600 (lc partials)

  prep_w1<<<50, 256, 0, stream>>>(conv1_w, wT1);
  conv1_v4<<<dim3(5, 9, 32), 256, 0, stream>>>(x, wT1, conv1_b, h1);
  pool_3_2_1<<<20164, 256, 0, stream>>>(h1, p1);
  t_xb2<<<dim3(32, 79), 256, 0, stream>>>(p1, xb2);
  prep_wb2<<<162, 256, 0, stream>>>(conv2_w, wb2);
  conv2_mfma<<<993, 256, 0, stream>>>(xb2, wb2, conv2_b, h2T);

  lc_v8<9, 1, 63, 55><<<dim3(190, 8), 256, 0, stream>>>(h2T, lc1_w, lcp);
  combineT<<<dim3(16, 48), 256, 0, stream>>>(lcp, lc1_b, h3T, 3025, 1548800, 8, 1);
  lc_v8<7, 2, 55, 25><<<dim3(40, 8), 256, 0, stream>>>(h3T, lc2_w, lcp);
  combineT<<<dim3(16, 10), 256, 0, stream>>>(lcp, lc2_b, h4T, 625, 320000, 8, 1);
  lc_v8<5, 1, 25, 21><<<dim3(28, 8), 256, 0, stream>>>(h4T, lc3_w, lcp);
  combineT<<<dim3(16, 7), 256, 0, stream>>>(lcp, lc3_b, h5T, 441, 225792, 8, 1);

  fc1_v2<<<512, 256, 0, stream>>>(h5T, fc1_w, fc1_b, out);
}

// Round 13
// 683.917 us; speedup vs baseline: 1.4570x; 1.1347x over previous
//
#include <hip/hip_runtime.h>
#include <cstddef>

typedef __attribute__((ext_vector_type(8))) short bf16x8;
typedef __attribute__((ext_vector_type(8), aligned(8))) short bf16x8a;
typedef __attribute__((ext_vector_type(4))) float f32x4;

__device__ inline unsigned short f2bf(float f) {
  unsigned int u = __float_as_uint(f);
  unsigned int r = (u + 0x7FFFu + ((u >> 16) & 1u)) >> 16;
  return (unsigned short)r;
}
__device__ inline float bf2f(unsigned short u) {
  return __uint_as_float((unsigned int)u << 16);
}

// ---------------- prep: x (32,3,152,152) f32 -> xb1 bf16 [b][ih152][iw160][ic4]
// iw >= 152 and ic slot 3 are zero.
__global__ __launch_bounds__(256) void prep_xb1(const float* __restrict__ x,
                                                unsigned short* __restrict__ xb) {
  const int j = blockIdx.x * 256 + threadIdx.x;   // 32*152*160 = 778240 exact
  const int iw = j % 160;
  const int ih = (j / 160) % 152;
  const int b = j / (160 * 152);
  unsigned short v[4] = {0, 0, 0, 0};
  if (iw < 152) {
    #pragma unroll
    for (int ic = 0; ic < 3; ++ic)
      v[ic] = f2bf(x[((size_t)(b * 3 + ic) * 152 + ih) * 152 + iw]);
  }
  *(unsigned long long*)(xb + (size_t)j * 4) = *(unsigned long long*)v;
}

// ---------------- prep: conv1 w (32,3,11,11) -> A-table wb1 [step17][kc4][s32][8]
// k = step*32 + kc*8 + e; tap t = step*8 + kc*2 + e/4; ic = e%4; kh=t/12, kwp=t%12.
__global__ __launch_bounds__(256) void prep_wb1(const float* __restrict__ w,
                                                unsigned short* __restrict__ wb) {
  const int j = blockIdx.x * 256 + threadIdx.x;   // 17*4*32*8 = 17408 exact
  const int e = j & 7;
  const int s = (j >> 3) & 31;                    // oc
  const int kcj = j >> 8;                         // step*4 + kc
  const int kc = kcj & 3, step = kcj >> 2;
  const int t = step * 8 + kc * 2 + (e >> 2);
  const int ics = e & 3;
  const int kh = t / 12, kwp = t - kh * 12;
  float val = 0.f;
  if (t < 132 && kwp < 11 && ics < 3)
    val = w[((s * 3 + ics) * 11 + kh) * 11 + kwp];
  wb[j] = f2bf(val);
}

// ---------------- conv1 via MFMA: wave = 1 pos; C[32oc][32b], K=544 (17 steps).
// B operand read direct from xb1 (8B-aligned bf16x8); A from wb1 table.
// Writes conv1T bf16 [oc32][pos20164][b32] with bias+relu fused.
__global__ __launch_bounds__(256, 4) void conv1_mfma(const unsigned short* __restrict__ xb,
                                                     const unsigned short* __restrict__ wb,
                                                     const float* __restrict__ bias,
                                                     unsigned short* __restrict__ outT) {
  const int lane = threadIdx.x & 63;
  const int wvi = threadIdx.x >> 6;
  const int pos = blockIdx.x * 4 + wvi;           // 5041*4 = 20164 exact
  const int oh = pos / 142, ow = pos % 142;
  const int row = lane & 15;                      // A row (oc) / B col (b)
  const int kc = lane >> 4;                       // k-chunk 0..3
  f32x4 a00 = {0.f, 0.f, 0.f, 0.f}, a01 = a00, a10 = a00, a11 = a00;
  const size_t xbase = ((size_t)row * 152 + oh) * 160 + ow;  // element/4 units

  #pragma unroll 2
  for (int j = 0; j < 17; ++j) {
    const int t0 = j * 8 + 2 * kc;
    int kh = t0 / 12;
    int kwp = t0 - kh * 12;
    if (t0 >= 132) { kh = 0; kwp = 0; }           // A rows are zero there
    const bf16x8 wa0 = *(const bf16x8*)(wb + (((j * 4 + kc) * 32) + row) * 8);
    const bf16x8 wa1 = *(const bf16x8*)(wb + (((j * 4 + kc) * 32) + 16 + row) * 8);
    const unsigned short* xp = xb + (xbase + kh * 160 + kwp) * 4;
    const bf16x8 xv0 = *(const bf16x8a*)(xp);
    const bf16x8 xv1 = *(const bf16x8a*)(xp + 16 * 152 * 160 * 4);
    a00 = __builtin_amdgcn_mfma_f32_16x16x32_bf16(wa0, xv0, a00, 0, 0, 0);
    a01 = __builtin_amdgcn_mfma_f32_16x16x32_bf16(wa0, xv1, a01, 0, 0, 0);
    a10 = __builtin_amdgcn_mfma_f32_16x16x32_bf16(wa1, xv0, a10, 0, 0, 0);
    a11 = __builtin_amdgcn_mfma_f32_16x16x32_bf16(wa1, xv1, a11, 0, 0, 0);
  }

  #pragma unroll
  for (int r = 0; r < 4; ++r) {
    const int ocl = kc * 4 + r;
    const float bv0 = bias[ocl];
    const float bv1 = bias[16 + ocl];
    outT[((size_t)ocl * 20164 + pos) * 32 + row] = f2bf(fmaxf(a00[r] + bv0, 0.f));
    outT[((size_t)ocl * 20164 + pos) * 32 + 16 + row] = f2bf(fmaxf(a01[r] + bv0, 0.f));
    outT[((size_t)(16 + ocl) * 20164 + pos) * 32 + row] = f2bf(fmaxf(a10[r] + bv1, 0.f));
    outT[((size_t)(16 + ocl) * 20164 + pos) * 32 + 16 + row] = f2bf(fmaxf(a11[r] + bv1, 0.f));
  }
}

// ---------------- fused maxpool(3,2,1) + transpose: conv1T [c32][pos20164][b32] bf16
// -> xb2 [pos'5041][b32][c32] bf16 (conv2_mfma's input layout).
__global__ __launch_bounds__(256) void pool_t(const unsigned short* __restrict__ in,
                                              unsigned short* __restrict__ xb) {
  __shared__ float tile[8][32][33];
  const int ohp = blockIdx.x;                     // 0..70
  const int t8 = blockIdx.y;                      // 0..8
  const int tid = threadIdx.x;
  const int b = tid & 31, pg = tid >> 5;          // 8 pos' per block
  const int owp = min(t8 * 8 + pg, 70);

  for (int c = 0; c < 32; ++c) {
    float m = 0.f;                                // relu'd inputs >= 0
    #pragma unroll
    for (int kh = 0; kh < 3; ++kh) {
      const int ih = ohp * 2 - 1 + kh;
      if (ih < 0 || ih >= 142) continue;
      #pragma unroll
      for (int kw = 0; kw < 3; ++kw) {
        const int iw = owp * 2 - 1 + kw;
        if (iw < 0 || iw >= 142) continue;
        m = fmaxf(m, bf2f(in[((size_t)c * 20164 + ih * 142 + iw) * 32 + b]));
      }
    }
    tile[pg][b][c] = m;
  }
  __syncthreads();

  if (t8 * 8 + pg < 71) {
    const int posp = ohp * 71 + t8 * 8 + pg;
    #pragma unroll
    for (int cc = 0; cc < 32; cc += 8) {
      bf16x8 pack;
      #pragma unroll
      for (int e = 0; e < 8; ++e) pack[e] = (short)f2bf(tile[pg][b][cc + e]);
      *(bf16x8*)(xb + ((size_t)posp * 32 + b) * 32 + cc) = pack;
    }
  }
}

// ---------------- wb2: conv2 w (16,32,9,9) -> [sp81][oc16][ic32] bf16
__global__ __launch_bounds__(256) void prep_wb2(const float* __restrict__ w,
                                                unsigned short* __restrict__ wb) {
  const int j = blockIdx.x * 256 + threadIdx.x;
  if (j >= 81 * 16 * 32) return;
  const int ic = j & 31, oc = (j >> 5) & 15, sp = j >> 9;
  wb[j] = f2bf(w[(size_t)oc * 2592 + ic * 81 + sp]);
}

// ---------------- conv2 via MFMA (proven): wave = 1 pos; 162 mfma 16x16x32 bf16.
__global__ __launch_bounds__(256) void conv2_mfma(const unsigned short* __restrict__ xb,
                                                  const unsigned short* __restrict__ wb,
                                                  const float* __restrict__ bias,
                                                  float* __restrict__ outT) {
  const int lane = threadIdx.x & 63;
  const int wvi = threadIdx.x >> 6;
  int pos = blockIdx.x * 4 + wvi;
  if (pos > 3968) pos = 3968;
  const int oh = pos / 63, ow = pos % 63;
  const int row = lane & 15;
  const int kc = lane >> 4;
  f32x4 acc0 = {0.f, 0.f, 0.f, 0.f}, acc1 = {0.f, 0.f, 0.f, 0.f};
  const unsigned short* xbase = xb + (size_t)(oh * 71 + ow) * 1024;
  const int aoff = row * 32 + kc * 8;
  const int boff0 = aoff;
  const int boff1 = (row + 16) * 32 + kc * 8;

  #pragma unroll
  for (int kh = 0; kh < 9; ++kh) {
    #pragma unroll
    for (int kw = 0; kw < 9; ++kw) {
      const int sp = kh * 9 + kw;
      const bf16x8 a = *(const bf16x8*)(wb + sp * 512 + aoff);
      const unsigned short* xp = xbase + (kh * 71 + kw) * 1024;
      const bf16x8 b0 = *(const bf16x8*)(xp + boff0);
      const bf16x8 b1 = *(const bf16x8*)(xp + boff1);
      acc0 = __builtin_amdgcn_mfma_f32_16x16x32_bf16(a, b0, acc0, 0, 0, 0);
      acc1 = __builtin_amdgcn_mfma_f32_16x16x32_bf16(a, b1, acc1, 0, 0, 0);
    }
  }

  #pragma unroll
  for (int r = 0; r < 4; ++r) {
    const int oc = kc * 4 + r;
    const float bv = bias[oc];
    outT[((size_t)oc * 3969 + pos) * 32 + row] = fmaxf(acc0[r] + bv, 0.f);
    outT[((size_t)oc * 3969 + pos) * 32 + 16 + row] = fmaxf(acc1[r] + bv, 0.f);
  }
}

// ---------------- combineT: sum nicg partials + bias + relu, output TRANSPOSED
__global__ __launch_bounds__(256) void combineT(const float* __restrict__ part,
                                                const float* __restrict__ bias,
                                                float* __restrict__ outT,
                                                int npos, int total, int nicg,
                                                int bias_pp) {
  __shared__ float tile[64][33];
  const int oc = blockIdx.x;
  const int pos0 = blockIdx.y * 64;
  const int tid = threadIdx.x;
  for (int j = tid; j < 2048; j += 256) {
    const int pl = j & 63;
    const int b = j >> 6;
    const int pos = min(pos0 + pl, npos - 1);
    const size_t idx = ((size_t)b * 16 + oc) * npos + pos;
    float v = 0.f;
    for (int g = 0; g < nicg; ++g) v += part[idx + (size_t)g * total];
    v += bias_pp ? bias[oc * npos + pos] : bias[oc];
    tile[pl][b] = fmaxf(v, 0.f);
  }
  __syncthreads();
  for (int j = tid; j < 2048; j += 256) {
    const int b = j & 31;
    const int pl = j >> 5;
    const int pos = pos0 + pl;
    if (pos < npos) outT[((size_t)oc * npos + pos) * 32 + b] = tile[pl][b];
  }
}

// ---------------- local conv v8: NO LDS. x pre-transposed to [ic][pos][b32].
template <int KH, int S, int IH, int OH>
__global__ __launch_bounds__(256, 4) void lc_v8(const float* __restrict__ xt,
                                                const float* __restrict__ w,
                                                float* __restrict__ part) {
  constexpr int KHW = KH * KH;
  constexpr int NPOS = OH * OH;
  constexpr int WOC = 16 * KHW;
  constexpr int KC4 = KHW / 4;               // 20 / 12 / 6
  const int tid = threadIdx.x;
  const int lane = tid & 63, wvi = tid >> 6;
  const int p = lane >> 4;
  const int og = (lane >> 3) & 1;
  const int bg = lane & 7;
  int mypos = blockIdx.x * 16 + wvi * 4 + p;
  if (mypos >= NPOS) mypos = NPOS - 1;
  const int icg = blockIdx.y;
  const int oh = mypos / OH, ow = mypos % OH;

  float acc[8][4] = {};
  #pragma unroll 1
  for (int ics = 0; ics < 2; ++ics) {
    const int ic = icg * 2 + ics;
    const float* wic = w + ((size_t)mypos * 16 + og * 8) * WOC + (size_t)ic * KHW;
    const float* xic =
        xt + (((size_t)ic * IH + oh * S) * IH + ow * S) * 32 + bg * 4;
    #pragma unroll 1
    for (int kc = 0; kc < KC4; ++kc) {
      float4 wf[8];
      #pragma unroll
      for (int o = 0; o < 8; ++o)
        wf[o] = *(const float4*)&wic[o * WOC + kc * 4];
      float4 xv[4];
      #pragma unroll
      for (int kk = 0; kk < 4; ++kk) {
        const int k = kc * 4 + kk;
        const int kh = k / KH, kw = k - kh * KH;
        xv[kk] = *(const float4*)&xic[(kh * IH + kw) * 32];
      }
      #pragma unroll
      for (int kk = 0; kk < 4; ++kk) {
        const float4 xk = xv[kk];
        #pragma unroll
        for (int o = 0; o < 8; ++o) {
          const float wv = (kk == 0) ? wf[o].x
                         : (kk == 1) ? wf[o].y
                         : (kk == 2) ? wf[o].z
                                     : wf[o].w;
          acc[o][0] += wv * xk.x;
          acc[o][1] += wv * xk.y;
          acc[o][2] += wv * xk.z;
          acc[o][3] += wv * xk.w;
        }
      }
    }
    {  // tail k = KHW-1
      const int k = KHW - 1;
      const float4 xk = *(const float4*)&xic[((KH - 1) * IH + (KH - 1)) * 32];
      #pragma unroll
      for (int o = 0; o < 8; ++o) {
        const float wv = wic[o * WOC + k];
        acc[o][0] += wv * xk.x;
        acc[o][1] += wv * xk.y;
        acc[o][2] += wv * xk.z;
        acc[o][3] += wv * xk.w;
      }
    }
  }

  float* pp = part + (size_t)icg * (32 * 16 * NPOS);
  #pragma unroll
  for (int o = 0; o < 8; ++o) {
    const int oc = og * 8 + o;
    #pragma unroll
    for (int i = 0; i < 4; ++i) {
      const int b = bg * 4 + i;
      pp[(((size_t)b * 16 + oc) * OH + oh) * OH + ow] = acc[o][i];
    }
  }
}

// ---------------- fc1: reg-tiled GEMM; xt = h5T ([oc][pos][b] == [k][b])
__global__ __launch_bounds__(256) void fc1_v2(const float* __restrict__ xt,
                                              const float* __restrict__ w,
                                              const float* __restrict__ bias,
                                              float* __restrict__ out) {
  const int lane = threadIdx.x & 63;
  const int b0 = (threadIdx.x >> 6) * 8;
  const int n0 = blockIdx.x * 8;
  float acc[8][8] = {};
  for (int it = 0; it < 28; ++it) {
    const int kb = it * 256 + lane * 4;
    float4 wf[8], xa[4], xb[4];
    if (kb < 7056) {
      #pragma unroll
      for (int n = 0; n < 8; ++n)
        wf[n] = *(const float4*)&w[(size_t)(n0 + n) * 7056 + kb];
      #pragma unroll
      for (int j = 0; j < 4; ++j) {
        xa[j] = *(const float4*)&xt[(size_t)(kb + j) * 32 + b0];
        xb[j] = *(const float4*)&xt[(size_t)(kb + j) * 32 + b0 + 4];
      }
    } else {
      #pragma unroll
      for (int n = 0; n < 8; ++n) wf[n] = make_float4(0.f, 0.f, 0.f, 0.f);
      #pragma unroll
      for (int j = 0; j < 4; ++j) {
        xa[j] = make_float4(0.f, 0.f, 0.f, 0.f);
        xb[j] = make_float4(0.f, 0.f, 0.f, 0.f);
      }
    }
    #pragma unroll
    for (int n = 0; n < 8; ++n) {
      const float wk[4] = {wf[n].x, wf[n].y, wf[n].z, wf[n].w};
      #pragma unroll
      for (int j = 0; j < 4; ++j) {
        acc[n][0] += wk[j] * xa[j].x;
        acc[n][1] += wk[j] * xa[j].y;
        acc[n][2] += wk[j] * xa[j].z;
        acc[n][3] += wk[j] * xa[j].w;
        acc[n][4] += wk[j] * xb[j].x;
        acc[n][5] += wk[j] * xb[j].y;
        acc[n][6] += wk[j] * xb[j].z;
        acc[n][7] += wk[j] * xb[j].w;
      }
    }
  }
  #pragma unroll
  for (int n = 0; n < 8; ++n)
    #pragma unroll
    for (int c = 0; c < 8; ++c)
      #pragma unroll
      for (int m = 1; m < 64; m <<= 1)
        acc[n][c] += __shfl_xor(acc[n][c], m, 64);
  float val = 0.f;
  #pragma unroll
  for (int n = 0; n < 8; ++n)
    #pragma unroll
    for (int c = 0; c < 8; ++c)
      if (lane == n * 8 + c) val = acc[n][c];
  const int n_l = lane >> 3, b_l = lane & 7;
  out[(size_t)(b0 + b_l) * 4096 + n0 + n_l] = val + bias[n0 + n_l];
}

extern "C" void kernel_launch(void* const* d_in, const int* in_sizes, int n_in,
                              void* d_out, int out_size, void* d_ws, size_t ws_size,
                              hipStream_t stream) {
  const float* x       = (const float*)d_in[0];
  const float* conv1_w = (const float*)d_in[1];
  const float* conv1_b = (const float*)d_in[2];
  const float* conv2_w = (const float*)d_in[3];
  const float* conv2_b = (const float*)d_in[4];
  const float* lc1_w   = (const float*)d_in[5];
  const float* lc1_b   = (const float*)d_in[6];
  const float* lc2_w   = (const float*)d_in[7];
  const float* lc2_b   = (const float*)d_in[8];
  const float* lc3_w   = (const float*)d_in[9];
  const float* lc3_b   = (const float*)d_in[10];
  const float* fc1_w   = (const float*)d_in[11];
  const float* fc1_b   = (const float*)d_in[12];
  float* out = (float*)d_out;
  char* ws = (char*)d_ws;

  // timeline-aware layout (bytes):
  unsigned short* xb1 = (unsigned short*)(ws + 0);         //  6,225,920 (conv1 input pack)
  unsigned short* wb1 = (unsigned short*)(ws + 6291456);   //     34,816
  unsigned short* c1T = (unsigned short*)(ws + 8388608);   // 41,295,872 (conv1 out bf16; dead after pool_t)
  unsigned short* xb2 = (unsigned short*)(ws + 50331648);  // 10,323,968 (dead after conv2_mfma)
  unsigned short* wb2 = (unsigned short*)(ws + 62914560);  //     82,944
  float* h2T          = (float*)(ws + 103239680);          //  8,128,512
  float* h3T          = (float*)(ws + 0);                  //  6,195,200 (xb1 dead by then)
  float* h4T          = (float*)(ws + 8388608);            //  1,280,000 (c1T dead)
  float* h5T          = (float*)(ws + 16777216);           //    903,168
  float* lcp          = (float*)(ws + 41943040);           // 49,561,600 (lc partials)

  prep_xb1<<<3040, 256, 0, stream>>>(x, xb1);
  prep_wb1<<<68, 256, 0, stream>>>(conv1_w, wb1);
  conv1_mfma<<<5041, 256, 0, stream>>>(xb1, wb1, conv1_b, c1T);
  pool_t<<<dim3(71, 9), 256, 0, stream>>>(c1T, xb2);
  prep_wb2<<<162, 256, 0, stream>>>(conv2_w, wb2);
  conv2_mfma<<<993, 256, 0, stream>>>(xb2, wb2, conv2_b, h2T);

  lc_v8<9, 1, 63, 55><<<dim3(190, 8), 256, 0, stream>>>(h2T, lc1_w, lcp);
  combineT<<<dim3(16, 48), 256, 0, stream>>>(lcp, lc1_b, h3T, 3025, 1548800, 8, 1);
  lc_v8<7, 2, 55, 25><<<dim3(40, 8), 256, 0, stream>>>(h3T, lc2_w, lcp);
  combineT<<<dim3(16, 10), 256, 0, stream>>>(lcp, lc2_b, h4T, 625, 320000, 8, 1);
  lc_v8<5, 1, 25, 21><<<dim3(28, 8), 256, 0, stream>>>(h4T, lc3_w, lcp);
  combineT<<<dim3(16, 7), 256, 0, stream>>>(lcp, lc3_b, h5T, 441, 225792, 8, 1);

  fc1_v2<<<512, 256, 0, stream>>>(h5T, fc1_w, fc1_b, out);
}

// Round 14
// 537.562 us; speedup vs baseline: 1.8537x; 1.2723x over previous
//
#include <hip/hip_runtime.h>
#include <cstddef>

typedef __attribute__((ext_vector_type(8))) short bf16x8;
typedef __attribute__((ext_vector_type(8), aligned(8))) short bf16x8a;
typedef __attribute__((ext_vector_type(4))) float f32x4;
typedef __attribute__((ext_vector_type(4))) unsigned short u16x4;

__device__ inline unsigned short f2bf(float f) {
  unsigned int u = __float_as_uint(f);
  unsigned int r = (u + 0x7FFFu + ((u >> 16) & 1u)) >> 16;
  return (unsigned short)r;
}
__device__ inline float bf2f(unsigned short u) {
  return __uint_as_float((unsigned int)u << 16);
}

// ---------------- prep: x (32,3,152,152) f32 -> xb1 bf16 [b][ih152][iw160][ic4]
__global__ __launch_bounds__(256) void prep_xb1(const float* __restrict__ x,
                                                unsigned short* __restrict__ xb) {
  const int j = blockIdx.x * 256 + threadIdx.x;   // 32*152*160 = 778240 exact
  const int iw = j % 160;
  const int ih = (j / 160) % 152;
  const int b = j / (160 * 152);
  unsigned short v[4] = {0, 0, 0, 0};
  if (iw < 152) {
    #pragma unroll
    for (int ic = 0; ic < 3; ++ic)
      v[ic] = f2bf(x[((size_t)(b * 3 + ic) * 152 + ih) * 152 + iw]);
  }
  *(unsigned long long*)(xb + (size_t)j * 4) = *(unsigned long long*)v;
}

// ---------------- prep: conv1 w (32,3,11,11) -> A-table wb1 [step17][kc4][s32][8]
__global__ __launch_bounds__(256) void prep_wb1(const float* __restrict__ w,
                                                unsigned short* __restrict__ wb) {
  const int j = blockIdx.x * 256 + threadIdx.x;   // 17408 exact
  const int e = j & 7;
  const int s = (j >> 3) & 31;
  const int kcj = j >> 8;
  const int kc = kcj & 3, step = kcj >> 2;
  const int t = step * 8 + kc * 2 + (e >> 2);
  const int ics = e & 3;
  const int kh = t / 12, kwp = t - kh * 12;
  float val = 0.f;
  if (t < 132 && kwp < 11 && ics < 3)
    val = w[((s * 3 + ics) * 11 + kh) * 11 + kwp];
  wb[j] = f2bf(val);
}

// ---------------- conv1 via MFMA (proven): writes c1T bf16 [oc32][pos20164][b32]
__global__ __launch_bounds__(256, 4) void conv1_mfma(const unsigned short* __restrict__ xb,
                                                     const unsigned short* __restrict__ wb,
                                                     const float* __restrict__ bias,
                                                     unsigned short* __restrict__ outT) {
  const int lane = threadIdx.x & 63;
  const int wvi = threadIdx.x >> 6;
  const int pos = blockIdx.x * 4 + wvi;
  const int oh = pos / 142, ow = pos % 142;
  const int row = lane & 15;
  const int kc = lane >> 4;
  f32x4 a00 = {0.f, 0.f, 0.f, 0.f}, a01 = a00, a10 = a00, a11 = a00;
  const size_t xbase = ((size_t)row * 152 + oh) * 160 + ow;

  #pragma unroll 2
  for (int j = 0; j < 17; ++j) {
    const int t0 = j * 8 + 2 * kc;
    int kh = t0 / 12;
    int kwp = t0 - kh * 12;
    if (t0 >= 132) { kh = 0; kwp = 0; }
    const bf16x8 wa0 = *(const bf16x8*)(wb + (((j * 4 + kc) * 32) + row) * 8);
    const bf16x8 wa1 = *(const bf16x8*)(wb + (((j * 4 + kc) * 32) + 16 + row) * 8);
    const unsigned short* xp = xb + (xbase + kh * 160 + kwp) * 4;
    const bf16x8 xv0 = *(const bf16x8a*)(xp);
    const bf16x8 xv1 = *(const bf16x8a*)(xp + 16 * 152 * 160 * 4);
    a00 = __builtin_amdgcn_mfma_f32_16x16x32_bf16(wa0, xv0, a00, 0, 0, 0);
    a01 = __builtin_amdgcn_mfma_f32_16x16x32_bf16(wa0, xv1, a01, 0, 0, 0);
    a10 = __builtin_amdgcn_mfma_f32_16x16x32_bf16(wa1, xv0, a10, 0, 0, 0);
    a11 = __builtin_amdgcn_mfma_f32_16x16x32_bf16(wa1, xv1, a11, 0, 0, 0);
  }

  #pragma unroll
  for (int r = 0; r < 4; ++r) {
    const int ocl = kc * 4 + r;
    const float bv0 = bias[ocl];
    const float bv1 = bias[16 + ocl];
    outT[((size_t)ocl * 20164 + pos) * 32 + row] = f2bf(fmaxf(a00[r] + bv0, 0.f));
    outT[((size_t)ocl * 20164 + pos) * 32 + 16 + row] = f2bf(fmaxf(a01[r] + bv0, 0.f));
    outT[((size_t)(16 + ocl) * 20164 + pos) * 32 + row] = f2bf(fmaxf(a10[r] + bv1, 0.f));
    outT[((size_t)(16 + ocl) * 20164 + pos) * 32 + 16 + row] = f2bf(fmaxf(a11[r] + bv1, 0.f));
  }
}

// ---------------- fused maxpool(3,2,1) + transpose -> xb2 [pos'5041][b32][c32] bf16
__global__ __launch_bounds__(256) void pool_t(const unsigned short* __restrict__ in,
                                              unsigned short* __restrict__ xb) {
  __shared__ float tile[8][32][33];
  const int ohp = blockIdx.x;
  const int t8 = blockIdx.y;
  const int tid = threadIdx.x;
  const int b = tid & 31, pg = tid >> 5;
  const int owp = min(t8 * 8 + pg, 70);

  for (int c = 0; c < 32; ++c) {
    float m = 0.f;
    #pragma unroll
    for (int kh = 0; kh < 3; ++kh) {
      const int ih = ohp * 2 - 1 + kh;
      if (ih < 0 || ih >= 142) continue;
      #pragma unroll
      for (int kw = 0; kw < 3; ++kw) {
        const int iw = owp * 2 - 1 + kw;
        if (iw < 0 || iw >= 142) continue;
        m = fmaxf(m, bf2f(in[((size_t)c * 20164 + ih * 142 + iw) * 32 + b]));
      }
    }
    tile[pg][b][c] = m;
  }
  __syncthreads();

  if (t8 * 8 + pg < 71) {
    const int posp = ohp * 71 + t8 * 8 + pg;
    #pragma unroll
    for (int cc = 0; cc < 32; cc += 8) {
      bf16x8 pack;
      #pragma unroll
      for (int e = 0; e < 8; ++e) pack[e] = (short)f2bf(tile[pg][b][cc + e]);
      *(bf16x8*)(xb + ((size_t)posp * 32 + b) * 32 + cc) = pack;
    }
  }
}

// ---------------- wb2: conv2 w (16,32,9,9) -> [sp81][oc16][ic32] bf16
__global__ __launch_bounds__(256) void prep_wb2(const float* __restrict__ w,
                                                unsigned short* __restrict__ wb) {
  const int j = blockIdx.x * 256 + threadIdx.x;
  if (j >= 81 * 16 * 32) return;
  const int ic = j & 31, oc = (j >> 5) & 15, sp = j >> 9;
  wb[j] = f2bf(w[(size_t)oc * 2592 + ic * 81 + sp]);
}

// ---------------- conv2 via MFMA; epilogue now writes h2b bf16 [pos][b32][oc16]
__global__ __launch_bounds__(256) void conv2_mfma(const unsigned short* __restrict__ xb,
                                                  const unsigned short* __restrict__ wb,
                                                  const float* __restrict__ bias,
                                                  unsigned short* __restrict__ outB) {
  const int lane = threadIdx.x & 63;
  const int wvi = threadIdx.x >> 6;
  int pos = blockIdx.x * 4 + wvi;
  if (pos > 3968) pos = 3968;
  const int oh = pos / 63, ow = pos % 63;
  const int row = lane & 15;                      // b column
  const int kc = lane >> 4;
  f32x4 acc0 = {0.f, 0.f, 0.f, 0.f}, acc1 = {0.f, 0.f, 0.f, 0.f};
  const unsigned short* xbase = xb + (size_t)(oh * 71 + ow) * 1024;
  const int aoff = row * 32 + kc * 8;
  const int boff0 = aoff;
  const int boff1 = (row + 16) * 32 + kc * 8;

  #pragma unroll
  for (int kh = 0; kh < 9; ++kh) {
    #pragma unroll
    for (int kw = 0; kw < 9; ++kw) {
      const int sp = kh * 9 + kw;
      const bf16x8 a = *(const bf16x8*)(wb + sp * 512 + aoff);
      const unsigned short* xp = xbase + (kh * 71 + kw) * 1024;
      const bf16x8 b0 = *(const bf16x8*)(xp + boff0);
      const bf16x8 b1 = *(const bf16x8*)(xp + boff1);
      acc0 = __builtin_amdgcn_mfma_f32_16x16x32_bf16(a, b0, acc0, 0, 0, 0);
      acc1 = __builtin_amdgcn_mfma_f32_16x16x32_bf16(a, b1, acc1, 0, 0, 0);
    }
  }

  u16x4 pk0, pk1;
  #pragma unroll
  for (int r = 0; r < 4; ++r) {
    const float bv = bias[kc * 4 + r];
    pk0[r] = f2bf(fmaxf(acc0[r] + bv, 0.f));
    pk1[r] = f2bf(fmaxf(acc1[r] + bv, 0.f));
  }
  *(u16x4*)(outB + (size_t)pos * 512 + row * 16 + kc * 4) = pk0;
  *(u16x4*)(outB + (size_t)pos * 512 + (row + 16) * 16 + kc * 4) = pk1;
}

// ---------------- lc weight prep: w [pos][oc16][ic16][KHW] f32 ->
// wbT bf16 [lpos][pair][oc16][tl2*ic16]; LDS-staged, coalesced read+write.
template <int KH>
__global__ __launch_bounds__(256) void prep_lcw(const float* __restrict__ w,
                                                unsigned short* __restrict__ wbT,
                                                int pos_base) {
  constexpr int KHW = KH * KH;
  constexpr int P = (KHW + 1) / 2;
  __shared__ float ls[8 * 16 * KHW];
  const int tid = threadIdx.x;
  const float* wp = w + (size_t)(pos_base + blockIdx.x) * (256 * KHW);
  unsigned short* ob = wbT + (size_t)blockIdx.x * (P * 512);

  for (int half = 0; half < 2; ++half) {
    __syncthreads();
    for (int j = tid; j < 8 * 16 * KHW; j += 256)
      ls[j] = wp[half * (8 * 16 * KHW) + j];
    __syncthreads();
    for (int j = tid; j < P * 256; j += 256) {
      const int ic = j & 15, tl = (j >> 4) & 1, oc8 = (j >> 5) & 7, pair = j >> 8;
      const int tap = pair * 2 + tl;
      const float v = (tap < KHW) ? ls[(oc8 * 16 + ic) * KHW + tap] : 0.f;
      ob[(size_t)pair * 512 + (half * 8 + oc8) * 32 + tl * 16 + ic] = f2bf(v);
    }
  }
}

// ---------------- lc via MFMA: wave = 1 pos; K = 2 taps x 16 ic per step.
// in xb [IH*IH][b32][ic16] bf16; out [NPOS][b32][oc16] bf16; bias[oc][pos].
template <int KH, int S, int IH, int OH>
__global__ __launch_bounds__(256) void lc_mfma(const unsigned short* __restrict__ xb,
                                               const unsigned short* __restrict__ wbT,
                                               const float* __restrict__ bias,
                                               unsigned short* __restrict__ out,
                                               int pos_base, int pos_count) {
  constexpr int KHW = KH * KH;
  constexpr int P = (KHW + 1) / 2;
  constexpr int NPOS = OH * OH;
  const int lane = threadIdx.x & 63;
  const int wvi = threadIdx.x >> 6;
  int lpos = blockIdx.x * 4 + wvi;
  if (lpos >= pos_count) lpos = pos_count - 1;
  const int pos = pos_base + lpos;
  const int oh = pos / OH, ow = pos % OH;
  const int bcol = lane & 15;
  const int kc = lane >> 4;
  const int tsel = kc >> 1;                        // which tap of the pair
  const int icoff = (kc & 1) * 8;
  f32x4 acc0 = {0.f, 0.f, 0.f, 0.f}, acc1 = {0.f, 0.f, 0.f, 0.f};
  const unsigned short* wp = wbT + (size_t)lpos * (P * 512) + bcol * 32 + kc * 8;
  const int xorg = (oh * S) * IH + ow * S;

  #pragma unroll
  for (int p = 0; p < P; ++p) {
    const int t0 = 2 * p;
    const int t1 = (2 * p + 1 < KHW) ? 2 * p + 1 : 2 * p;
    const int o0 = (t0 / KH) * IH + (t0 % KH);
    const int o1 = (t1 / KH) * IH + (t1 % KH);
    const int osel = tsel ? o1 : o0;
    const bf16x8 a = *(const bf16x8*)(wp + p * 512);
    const unsigned short* xp = xb + (size_t)(xorg + osel) * 512 + icoff;
    const bf16x8 b0 = *(const bf16x8*)(xp + bcol * 16);
    const bf16x8 b1 = *(const bf16x8*)(xp + (bcol + 16) * 16);
    acc0 = __builtin_amdgcn_mfma_f32_16x16x32_bf16(a, b0, acc0, 0, 0, 0);
    acc1 = __builtin_amdgcn_mfma_f32_16x16x32_bf16(a, b1, acc1, 0, 0, 0);
  }

  u16x4 pk0, pk1;
  #pragma unroll
  for (int r = 0; r < 4; ++r) {
    const float bv = bias[(kc * 4 + r) * NPOS + pos];
    pk0[r] = f2bf(fmaxf(acc0[r] + bv, 0.f));
    pk1[r] = f2bf(fmaxf(acc1[r] + bv, 0.f));
  }
  *(u16x4*)(out + (size_t)pos * 512 + bcol * 16 + kc * 4) = pk0;
  *(u16x4*)(out + (size_t)pos * 512 + (bcol + 16) * 16 + kc * 4) = pk1;
}

// ---------------- reformat lc3 out [pos441][b32][oc16] bf16 -> h5T f32 [oc*441+pos][b32]
__global__ __launch_bounds__(256) void fc_reformat(const unsigned short* __restrict__ xb5,
                                                   float* __restrict__ h5T) {
  const int j = blockIdx.x * 256 + threadIdx.x;   // 225792 exact
  const int b = j & 31;
  const int pos = (j >> 5) % 441;
  const int oc = j / (441 * 32);
  h5T[j] = bf2f(xb5[((size_t)pos * 32 + b) * 16 + oc]);
}

// ---------------- fc1: reg-tiled GEMM (unchanged)
__global__ __launch_bounds__(256) void fc1_v2(const float* __restrict__ xt,
                                              const float* __restrict__ w,
                                              const float* __restrict__ bias,
                                              float* __restrict__ out) {
  const int lane = threadIdx.x & 63;
  const int b0 = (threadIdx.x >> 6) * 8;
  const int n0 = blockIdx.x * 8;
  float acc[8][8] = {};
  for (int it = 0; it < 28; ++it) {
    const int kb = it * 256 + lane * 4;
    float4 wf[8], xa[4], xb[4];
    if (kb < 7056) {
      #pragma unroll
      for (int n = 0; n < 8; ++n)
        wf[n] = *(const float4*)&w[(size_t)(n0 + n) * 7056 + kb];
      #pragma unroll
      for (int j = 0; j < 4; ++j) {
        xa[j] = *(const float4*)&xt[(size_t)(kb + j) * 32 + b0];
        xb[j] = *(const float4*)&xt[(size_t)(kb + j) * 32 + b0 + 4];
      }
    } else {
      #pragma unroll
      for (int n = 0; n < 8; ++n) wf[n] = make_float4(0.f, 0.f, 0.f, 0.f);
      #pragma unroll
      for (int j = 0; j < 4; ++j) {
        xa[j] = make_float4(0.f, 0.f, 0.f, 0.f);
        xb[j] = make_float4(0.f, 0.f, 0.f, 0.f);
      }
    }
    #pragma unroll
    for (int n = 0; n < 8; ++n) {
      const float wk[4] = {wf[n].x, wf[n].y, wf[n].z, wf[n].w};
      #pragma unroll
      for (int j = 0; j < 4; ++j) {
        acc[n][0] += wk[j] * xa[j].x;
        acc[n][1] += wk[j] * xa[j].y;
        acc[n][2] += wk[j] * xa[j].z;
        acc[n][3] += wk[j] * xa[j].w;
        acc[n][4] += wk[j] * xb[j].x;
        acc[n][5] += wk[j] * xb[j].y;
        acc[n][6] += wk[j] * xb[j].z;
        acc[n][7] += wk[j] * xb[j].w;
      }
    }
  }
  #pragma unroll
  for (int n = 0; n < 8; ++n)
    #pragma unroll
    for (int c = 0; c < 8; ++c)
      #pragma unroll
      for (int m = 1; m < 64; m <<= 1)
        acc[n][c] += __shfl_xor(acc[n][c], m, 64);
  float val = 0.f;
  #pragma unroll
  for (int n = 0; n < 8; ++n)
    #pragma unroll
    for (int c = 0; c < 8; ++c)
      if (lane == n * 8 + c) val = acc[n][c];
  const int n_l = lane >> 3, b_l = lane & 7;
  out[(size_t)(b0 + b_l) * 4096 + n0 + n_l] = val + bias[n0 + n_l];
}

extern "C" void kernel_launch(void* const* d_in, const int* in_sizes, int n_in,
                              void* d_out, int out_size, void* d_ws, size_t ws_size,
                              hipStream_t stream) {
  const float* x       = (const float*)d_in[0];
  const float* conv1_w = (const float*)d_in[1];
  const float* conv1_b = (const float*)d_in[2];
  const float* conv2_w = (const float*)d_in[3];
  const float* conv2_b = (const float*)d_in[4];
  const float* lc1_w   = (const float*)d_in[5];
  const float* lc1_b   = (const float*)d_in[6];
  const float* lc2_w   = (const float*)d_in[7];
  const float* lc2_b   = (const float*)d_in[8];
  const float* lc3_w   = (const float*)d_in[9];
  const float* lc3_b   = (const float*)d_in[10];
  const float* fc1_w   = (const float*)d_in[11];
  const float* fc1_b   = (const float*)d_in[12];
  float* out = (float*)d_out;
  char* ws = (char*)d_ws;

  // timeline-aware layout (bytes), peak ~78.5 MB:
  unsigned short* xb1 = (unsigned short*)(ws + 0);         //  6,225,920 (dead after conv1)
  unsigned short* wb1 = (unsigned short*)(ws + 6291456);   //     34,816
  unsigned short* c1T = (unsigned short*)(ws + 8388608);   // 41,295,872 (dead after pool_t)
  unsigned short* xb2 = (unsigned short*)(ws + 50331648);  // 10,323,968 (dead after conv2)
  unsigned short* wb2 = (unsigned short*)(ws + 62914560);  //     82,944 (dead after conv2)
  unsigned short* h2b = (unsigned short*)(ws + 67108864);  //  4,064,256 (dead after lc1)
  unsigned short* xb3 = (unsigned short*)(ws + 71303168);  //  3,097,600 (dead after lc2)
  unsigned short* xb4 = (unsigned short*)(ws + 75497472);  //    640,000 (dead after lc3)
  unsigned short* xb5 = (unsigned short*)(ws + 76546048);  //    451,584
  float* h5T          = (float*)(ws + 77594624);           //    903,168
  unsigned short* wbT = (unsigned short*)(ws + 0);         // <= 63,521,792 (lc weight chunks; all earlier buffers at <67MB dead)

  prep_xb1<<<3040, 256, 0, stream>>>(x, xb1);
  prep_wb1<<<68, 256, 0, stream>>>(conv1_w, wb1);
  conv1_mfma<<<5041, 256, 0, stream>>>(xb1, wb1, conv1_b, c1T);
  pool_t<<<dim3(71, 9), 256, 0, stream>>>(c1T, xb2);
  prep_wb2<<<162, 256, 0, stream>>>(conv2_w, wb2);
  conv2_mfma<<<993, 256, 0, stream>>>(xb2, wb2, conv2_b, h2b);

  // lc1 in two weight chunks (63.5 MB each)
  prep_lcw<9><<<1513, 256, 0, stream>>>(lc1_w, wbT, 0);
  lc_mfma<9, 1, 63, 55><<<379, 256, 0, stream>>>(h2b, wbT, lc1_b, xb3, 0, 1513);
  prep_lcw<9><<<1512, 256, 0, stream>>>(lc1_w, wbT, 1513);
  lc_mfma<9, 1, 63, 55><<<378, 256, 0, stream>>>(h2b, wbT, lc1_b, xb3, 1513, 1512);

  prep_lcw<7><<<625, 256, 0, stream>>>(lc2_w, wbT, 0);
  lc_mfma<7, 2, 55, 25><<<157, 256, 0, stream>>>(xb3, wbT, lc2_b, xb4, 0, 625);

  prep_lcw<5><<<441, 256, 0, stream>>>(lc3_w, wbT, 0);
  lc_mfma<5, 1, 25, 21><<<111, 256, 0, stream>>>(xb4, wbT, lc3_b, xb5, 0, 441);

  fc_reformat<<<882, 256, 0, stream>>>(xb5, h5T);
  fc1_v2<<<512, 256, 0, stream>>>(h5T, fc1_w, fc1_b, out);
}